// Round 5
// baseline (517.763 us; speedup 1.0000x reference)
//
#include <hip/hip_runtime.h>
#include <math.h>

#define NPTS 16384
#define DIM  24
#define KPAD 32
#define ESIG 65536
#define ERND 32768
#define THRESH 2.0f
#define LDSS 36      // 72 B LDS row stride: row-banks walk all 16 even banks -> 2-way max (free)
#define CAP  8192
#define NBLK 4160    // triangular block count: sum_{bi<64}(128-2*bi)

typedef __attribute__((ext_vector_type(8))) short bf16x8;
typedef __attribute__((ext_vector_type(4))) float f32x4;

// ws layout:
//   float sigP[128]; float rndP[64]; int cnt[4]; int cand[2*CAP];
//   ushort Ab[16384*32]; ushort Bb[16384*32];

__device__ __forceinline__ unsigned short f2bf(float x) {
    unsigned int u = __float_as_uint(x);
    unsigned int r = u + 0x7fffu + ((u >> 16) & 1u);
    return (unsigned short)(r >> 16);
}

__device__ __forceinline__ float min3f(float a, float b, float c) {
    return fminf(fminf(a, b), c);   // fuses to v_min3_f32
}

__device__ __forceinline__ float wave_reduce(float v) {
#pragma unroll
    for (int off = 32; off > 0; off >>= 1)
        v += __shfl_down(v, off, 64);
    return v;
}

__device__ __forceinline__ void block_reduce_store(float v, float* slot) {
    __shared__ float red[8];
    int lane = threadIdx.x & 63;
    int wid  = threadIdx.x >> 6;
    v = wave_reduce(v);
    if (lane == 0) red[wid] = v;
    __syncthreads();
    if (threadIdx.x == 0) {
        float s = 0.f;
        int nw = blockDim.x >> 6;
        for (int w = 0; w < nw; ++w) s += red[w];
        *slot = s;
    }
}

__device__ __forceinline__ float edge_d2(const float* __restrict__ emb, int a, int b) {
    const float4* ra = reinterpret_cast<const float4*>(emb + (size_t)a * DIM);
    const float4* rb = reinterpret_cast<const float4*>(emb + (size_t)b * DIM);
    float d2 = 0.f;
#pragma unroll
    for (int k = 0; k < 6; ++k) {
        float4 va = ra[k], vb = rb[k];
        float dx = va.x - vb.x, dy = va.y - vb.y;
        float dz = va.z - vb.z, dw = va.w - vb.w;
        d2 += dx * dx; d2 += dy * dy; d2 += dz * dz; d2 += dw * dw;
    }
    return d2;
}

// blocks [0,64): prep Ab/Bb; [64,192): signal edges (512/block); [192,256): random edges
__global__ __launch_bounds__(256) void fused_pre_kernel(
    const float* __restrict__ emb, const int* __restrict__ sedge,
    const int* __restrict__ redge, const int* __restrict__ pid,
    unsigned short* __restrict__ Ab, unsigned short* __restrict__ Bb,
    float* __restrict__ sigP, float* __restrict__ rndP, int* __restrict__ cnt)
{
    int b = blockIdx.x, t = threadIdx.x;
    if (b < 64) {
        if (b == 0 && t == 0) { cnt[0] = 0; cnt[1] = 0; }
        int i = b * 256 + t;
        const float4* rp = reinterpret_cast<const float4*>(emb + (size_t)i * DIM);
        float v[24];
        float s = 0.f;
#pragma unroll
        for (int k = 0; k < 6; ++k) {
            float4 q = rp[k];
            v[4*k+0] = q.x; v[4*k+1] = q.y; v[4*k+2] = q.z; v[4*k+3] = q.w;
            s += q.x*q.x + q.y*q.y + q.z*q.z + q.w*q.w;
        }
        union { unsigned short u[32]; int4 q[4]; } a, bb;
#pragma unroll
        for (int k = 0; k < 24; ++k) { a.u[k] = f2bf(-2.f * v[k]); bb.u[k] = f2bf(v[k]); }
        a.u[24] = f2bf(s);   a.u[25] = f2bf(1.f);
        bb.u[24] = f2bf(1.f); bb.u[25] = f2bf(s);
#pragma unroll
        for (int k = 26; k < 32; ++k) { a.u[k] = 0; bb.u[k] = 0; }
        int4* pa = reinterpret_cast<int4*>(Ab + (size_t)i * KPAD);
        int4* pb = reinterpret_cast<int4*>(Bb + (size_t)i * KPAD);
#pragma unroll
        for (int k = 0; k < 4; ++k) { pa[k] = a.q[k]; pb[k] = bb.q[k]; }
    } else if (b < 192) {
        int eb = b - 64;                 // 128 blocks, 512 edges each, 2/thread
        int e0 = eb * 512 + t, e1 = e0 + 256;
        int a0 = sedge[e0], b0 = sedge[ESIG + e0];
        int a1 = sedge[e1], b1 = sedge[ESIG + e1];
        float d2 = edge_d2(emb, a0, b0) + edge_d2(emb, a1, b1) + 2e-12f;
        block_reduce_store(d2, &sigP[eb]);
    } else {
        int eb = b - 192;                // 64 blocks, 512 edges each, 2/thread
        int e0 = eb * 512 + t, e1 = e0 + 256;
        int a0 = redge[e0], b0 = redge[ERND + e0];
        int a1 = redge[e1], b1 = redge[ERND + e1];
        float val = 0.f;
        if (pid[a0] != pid[b0]) {
            float d = sqrtf(edge_d2(emb, a0, b0) + 1e-12f);
            float h = 1.f - d;
            if (h > 0.f) val = h * h;
        }
        if (pid[a1] != pid[b1]) {
            float d = sqrtf(edge_d2(emb, a1, b1) + 1e-12f);
            float h = 1.f - d;
            if (h > 0.f) val += h * h;
        }
        block_reduce_store(val, &rndP[eb]);
    }
}

// One-shot 256x128 tile per block; compacted triangular grid (bj >= 2*bi).
// 8 waves (4x2), each wave 64x64 = 16 MFMA. Last finishing block does the
// exact fp32 recheck of candidates + final reduction (fan-in pattern).
__global__ __launch_bounds__(512) void knn_mfma_kernel(
    const unsigned short* __restrict__ Ab, const unsigned short* __restrict__ Bb,
    const float* __restrict__ emb, const int* __restrict__ pid,
    const float* __restrict__ sigP, const float* __restrict__ rndP,
    int* __restrict__ cnt, int* __restrict__ cand, float* __restrict__ out)
{
    // recover (bi, bj) from compact id: C(bi) = bi*(129-bi), bj = 2*bi + (id - C(bi))
    const int id = blockIdx.x;
    int bi = (int)((129.0f - sqrtf(16641.0f - 4.0f * (float)id)) * 0.5f);
    while (bi * (129 - bi) > id) --bi;
    while ((bi + 1) * (129 - (bi + 1)) <= id) ++bi;
    const int bj = 2 * bi + (id - bi * (129 - bi));

    __shared__ short lB[128 * LDSS];
    __shared__ int isLast;
    const int t  = threadIdx.x;
    const int i0 = bi * 256, j0 = bj * 128;

    // stage B panel: 128 rows x 64 B, one int4 per thread (coalesced)
    {
        int row = t >> 2, q = t & 3;
        int4 v = *reinterpret_cast<const int4*>(Bb + (size_t)(j0 + row) * KPAD + q * 8);
        *reinterpret_cast<int4*>(&lB[row * LDSS + q * 8]) = v;
    }

    const int wid = t >> 6, lane = t & 63;
    const int wr = wid >> 1, wc = wid & 1;          // 4x2 wave grid
    const int lrow = lane & 15, lkb = (lane >> 4) * 8;

    // A fragments: direct global, 1 KB contiguous per instruction per wave
    bf16x8 af[4];
#pragma unroll
    for (int r = 0; r < 4; ++r)
        af[r] = *reinterpret_cast<const bf16x8*>(
            Ab + (size_t)(i0 + wr * 64 + r * 16 + lrow) * KPAD + lkb);

    __syncthreads();

    bf16x8 bfr[4];
#pragma unroll
    for (int c = 0; c < 4; ++c)
        bfr[c] = *reinterpret_cast<const bf16x8*>(
            &lB[(wc * 64 + c * 16 + lrow) * LDSS + lkb]);

    const f32x4 zero = {0.f, 0.f, 0.f, 0.f};
    f32x4 acc[4][4];
#pragma unroll
    for (int r = 0; r < 4; ++r)
#pragma unroll
        for (int c = 0; c < 4; ++c)
            acc[r][c] = __builtin_amdgcn_mfma_f32_16x16x32_bf16(af[r], bfr[c], zero, 0, 0, 0);

    // min over the 64 d^2 values this lane holds (min3 trees)
    float tm[16];
#pragma unroll
    for (int r = 0; r < 4; ++r)
#pragma unroll
        for (int c = 0; c < 4; ++c)
            tm[r * 4 + c] = fminf(min3f(acc[r][c][0], acc[r][c][1], acc[r][c][2]),
                                  acc[r][c][3]);
    float m0 = min3f(tm[0], tm[1], tm[2]);
    float m1 = min3f(tm[3], tm[4], tm[5]);
    float m2 = min3f(tm[6], tm[7], tm[8]);
    float m3 = min3f(tm[9], tm[10], tm[11]);
    float m4 = min3f(tm[12], tm[13], tm[14]);
    float mn = fminf(min3f(min3f(m0, m1, m2), m3, m4), tm[15]);

    if (mn < THRESH) {   // fires only for diagonal cells / true near-pairs
#pragma unroll
        for (int r = 0; r < 4; ++r)
#pragma unroll
            for (int c = 0; c < 4; ++c)
#pragma unroll
                for (int e = 0; e < 4; ++e) {
                    if (acc[r][c][e] < THRESH) {
                        int i = i0 + wr * 64 + r * 16 + (lane >> 4) * 4 + e;
                        int j = j0 + wc * 64 + c * 16 + (lane & 15);
                        if (i < j) {
                            int slot = atomicAdd(&cnt[0], 1);
                            if (slot < CAP) {
                                cand[2 * slot]     = i;
                                cand[2 * slot + 1] = j;
                            }
                        }
                    }
                }
    }

    // fan-in: last block to finish does the finalize
    __threadfence();
    __syncthreads();
    if (t == 0) {
        int done = atomicAdd(&cnt[1], 1);
        isLast = (done == NBLK - 1);
    }
    __syncthreads();
    if (!isLast) return;

    __threadfence();   // acquire: see all blocks' cand/cnt writes
    int n = cnt[0];
    if (n > CAP) n = CAP;
    float ca = 0.f;
    for (int k = t; k < n; k += 512) {
        int i = cand[2 * k], j = cand[2 * k + 1];
        if (pid[i] != pid[j]) {
            float d = sqrtf(fmaxf(edge_d2(emb, i, j), 0.f) + 1e-12f);
            if (d < 1.f) { float h = 1.f - d; ca += h * h; }
        }
    }
    float v = ca * (2.f / NPTS);
    if (t < 128) v += sigP[t] * (1.f / ESIG);
    if (t < 64)  v += rndP[t] * (1.f / ERND);
    block_reduce_store(v, out);
}

extern "C" void kernel_launch(void* const* d_in, const int* in_sizes, int n_in,
                              void* d_out, int out_size, void* d_ws, size_t ws_size,
                              hipStream_t stream) {
    const float* emb   = (const float*)d_in[0];
    const int*   sedge = (const int*)d_in[1];
    const int*   redge = (const int*)d_in[2];
    const int*   pid   = (const int*)d_in[3];
    float* out = (float*)d_out;

    float* sigP = (float*)d_ws;                       // 128
    float* rndP = sigP + 128;                         // 64
    int*   cnt  = (int*)(rndP + 64);                  // 4 (cand count, done ticket)
    int*   cand = cnt + 4;                            // 2*CAP
    unsigned short* Ab = (unsigned short*)(cand + 2 * CAP);   // 16384*32
    unsigned short* Bb = Ab + (size_t)NPTS * KPAD;            // 16384*32

    fused_pre_kernel<<<256, 256, 0, stream>>>(emb, sedge, redge, pid, Ab, Bb, sigP, rndP, cnt);
    knn_mfma_kernel<<<NBLK, 512, 0, stream>>>(Ab, Bb, emb, pid, sigP, rndP, cnt, cand, out);
}

// Round 6
// 32.074 us; speedup vs baseline: 16.1429x; 16.1429x over previous
//
#include <hip/hip_runtime.h>
#include <math.h>

#define NPTS 16384
#define DIM  24
#define KPAD 32
#define ESIG 65536
#define ERND 32768
#define THRESH 2.0f
#define CAP  8192
#define NBLK 4160    // triangular block count: sum_{bi<64}(128-2*bi)

typedef __attribute__((ext_vector_type(8))) short bf16x8;
typedef __attribute__((ext_vector_type(4))) float f32x4;

// ws layout:
//   float sigP[128]; float rndP[64]; int cnt[4]; int cand[2*CAP];
//   ushort Ab[16384*32]; ushort Bb[16384*32];

__device__ __forceinline__ unsigned short f2bf(float x) {
    unsigned int u = __float_as_uint(x);
    unsigned int r = u + 0x7fffu + ((u >> 16) & 1u);
    return (unsigned short)(r >> 16);
}

__device__ __forceinline__ float min3f(float a, float b, float c) {
    return fminf(fminf(a, b), c);   // fuses to v_min3_f32
}

__device__ __forceinline__ float wave_reduce(float v) {
#pragma unroll
    for (int off = 32; off > 0; off >>= 1)
        v += __shfl_down(v, off, 64);
    return v;
}

__device__ __forceinline__ void block_reduce_store(float v, float* slot) {
    __shared__ float red[8];
    int lane = threadIdx.x & 63;
    int wid  = threadIdx.x >> 6;
    v = wave_reduce(v);
    if (lane == 0) red[wid] = v;
    __syncthreads();
    if (threadIdx.x == 0) {
        float s = 0.f;
        int nw = blockDim.x >> 6;
        for (int w = 0; w < nw; ++w) s += red[w];
        *slot = s;
    }
}

__device__ __forceinline__ float edge_d2(const float* __restrict__ emb, int a, int b) {
    const float4* ra = reinterpret_cast<const float4*>(emb + (size_t)a * DIM);
    const float4* rb = reinterpret_cast<const float4*>(emb + (size_t)b * DIM);
    float d2 = 0.f;
#pragma unroll
    for (int k = 0; k < 6; ++k) {
        float4 va = ra[k], vb = rb[k];
        float dx = va.x - vb.x, dy = va.y - vb.y;
        float dz = va.z - vb.z, dw = va.w - vb.w;
        d2 += dx * dx; d2 += dy * dy; d2 += dz * dz; d2 += dw * dw;
    }
    return d2;
}

// blocks [0,64): prep Ab/Bb; [64,192): signal edges (512/block); [192,256): random edges
__global__ __launch_bounds__(256) void fused_pre_kernel(
    const float* __restrict__ emb, const int* __restrict__ sedge,
    const int* __restrict__ redge, const int* __restrict__ pid,
    unsigned short* __restrict__ Ab, unsigned short* __restrict__ Bb,
    float* __restrict__ sigP, float* __restrict__ rndP, int* __restrict__ cnt)
{
    int b = blockIdx.x, t = threadIdx.x;
    if (b < 64) {
        if (b == 0 && t == 0) cnt[0] = 0;
        int i = b * 256 + t;
        const float4* rp = reinterpret_cast<const float4*>(emb + (size_t)i * DIM);
        float v[24];
        float s = 0.f;
#pragma unroll
        for (int k = 0; k < 6; ++k) {
            float4 q = rp[k];
            v[4*k+0] = q.x; v[4*k+1] = q.y; v[4*k+2] = q.z; v[4*k+3] = q.w;
            s += q.x*q.x + q.y*q.y + q.z*q.z + q.w*q.w;
        }
        union { unsigned short u[32]; int4 q[4]; } a, bb;
#pragma unroll
        for (int k = 0; k < 24; ++k) { a.u[k] = f2bf(-2.f * v[k]); bb.u[k] = f2bf(v[k]); }
        a.u[24] = f2bf(s);   a.u[25] = f2bf(1.f);
        bb.u[24] = f2bf(1.f); bb.u[25] = f2bf(s);
#pragma unroll
        for (int k = 26; k < 32; ++k) { a.u[k] = 0; bb.u[k] = 0; }
        int4* pa = reinterpret_cast<int4*>(Ab + (size_t)i * KPAD);
        int4* pb = reinterpret_cast<int4*>(Bb + (size_t)i * KPAD);
#pragma unroll
        for (int k = 0; k < 4; ++k) { pa[k] = a.q[k]; pb[k] = bb.q[k]; }
    } else if (b < 192) {
        int eb = b - 64;                 // 128 blocks, 512 edges each, 2/thread
        int e0 = eb * 512 + t, e1 = e0 + 256;
        int a0 = sedge[e0], b0 = sedge[ESIG + e0];
        int a1 = sedge[e1], b1 = sedge[ESIG + e1];
        float d2 = edge_d2(emb, a0, b0) + edge_d2(emb, a1, b1) + 2e-12f;
        block_reduce_store(d2, &sigP[eb]);
    } else {
        int eb = b - 192;                // 64 blocks, 512 edges each, 2/thread
        int e0 = eb * 512 + t, e1 = e0 + 256;
        int a0 = redge[e0], b0 = redge[ERND + e0];
        int a1 = redge[e1], b1 = redge[ERND + e1];
        float val = 0.f;
        if (pid[a0] != pid[b0]) {
            float d = sqrtf(edge_d2(emb, a0, b0) + 1e-12f);
            float h = 1.f - d;
            if (h > 0.f) val = h * h;
        }
        if (pid[a1] != pid[b1]) {
            float d = sqrtf(edge_d2(emb, a1, b1) + 1e-12f);
            float h = 1.f - d;
            if (h > 0.f) val += h * h;
        }
        block_reduce_store(val, &rndP[eb]);
    }
}

// 256x128 tile per block, compact triangular grid (bj >= 2*bi).
// NO LDS, NO barriers: each of the 8 waves (4x2) loads its own A/B fragments
// direct from global (L2-resident; 4-wave B redundancy absorbed by L1).
__global__ __launch_bounds__(512) void knn_mfma_kernel(
    const unsigned short* __restrict__ Ab, const unsigned short* __restrict__ Bb,
    int* __restrict__ cnt, int* __restrict__ cand)
{
    // recover (bi, bj) from compact id: C(bi) = bi*(129-bi), bj = 2*bi + (id - C(bi))
    const int id = blockIdx.x;
    int bi = (int)((129.0f - sqrtf(16641.0f - 4.0f * (float)id)) * 0.5f);
    while (bi * (129 - bi) > id) --bi;
    while ((bi + 1) * (129 - (bi + 1)) <= id) ++bi;
    const int bj = 2 * bi + (id - bi * (129 - bi));

    const int t = threadIdx.x;
    const int wid = t >> 6, lane = t & 63;
    const int wr = wid >> 1, wc = wid & 1;          // 4x2 wave grid
    const int i0 = bi * 256, j0 = bj * 128;
    const int lrow = lane & 15, lkb = (lane >> 4) * 8;

    bf16x8 af[4], bfr[4];
#pragma unroll
    for (int r = 0; r < 4; ++r)
        af[r] = *reinterpret_cast<const bf16x8*>(
            Ab + (size_t)(i0 + wr * 64 + r * 16 + lrow) * KPAD + lkb);
#pragma unroll
    for (int c = 0; c < 4; ++c)
        bfr[c] = *reinterpret_cast<const bf16x8*>(
            Bb + (size_t)(j0 + wc * 64 + c * 16 + lrow) * KPAD + lkb);

    const f32x4 zero = {0.f, 0.f, 0.f, 0.f};
    f32x4 acc[4][4];
#pragma unroll
    for (int r = 0; r < 4; ++r)
#pragma unroll
        for (int c = 0; c < 4; ++c)
            acc[r][c] = __builtin_amdgcn_mfma_f32_16x16x32_bf16(af[r], bfr[c], zero, 0, 0, 0);

    // min over the 64 d^2 values this lane holds (min3 trees)
    float tm[16];
#pragma unroll
    for (int r = 0; r < 4; ++r)
#pragma unroll
        for (int c = 0; c < 4; ++c)
            tm[r * 4 + c] = fminf(min3f(acc[r][c][0], acc[r][c][1], acc[r][c][2]),
                                  acc[r][c][3]);
    float m0 = min3f(tm[0], tm[1], tm[2]);
    float m1 = min3f(tm[3], tm[4], tm[5]);
    float m2 = min3f(tm[6], tm[7], tm[8]);
    float m3 = min3f(tm[9], tm[10], tm[11]);
    float m4 = min3f(tm[12], tm[13], tm[14]);
    float mn = fminf(min3f(min3f(m0, m1, m2), m3, m4), tm[15]);

    if (mn < THRESH) {   // fires only for diagonal cells / true near-pairs
#pragma unroll
        for (int r = 0; r < 4; ++r)
#pragma unroll
            for (int c = 0; c < 4; ++c)
#pragma unroll
                for (int e = 0; e < 4; ++e) {
                    if (acc[r][c][e] < THRESH) {
                        int i = i0 + wr * 64 + r * 16 + (lane >> 4) * 4 + e;
                        int j = j0 + wc * 64 + c * 16 + (lane & 15);
                        if (i < j) {
                            int slot = atomicAdd(&cnt[0], 1);
                            if (slot < CAP) {
                                cand[2 * slot]     = i;
                                cand[2 * slot + 1] = j;
                            }
                        }
                    }
                }
    }
}

// exact fp32 recheck of candidates (weight 2: i<j only) + final reduction
__global__ __launch_bounds__(256) void finalize_kernel(
    const float* __restrict__ emb, const int* __restrict__ pid,
    const int* __restrict__ cnt, const int* __restrict__ cand,
    const float* __restrict__ sigP, const float* __restrict__ rndP,
    float* __restrict__ out)
{
    int t = threadIdx.x;
    int n = cnt[0];
    if (n > CAP) n = CAP;
    float ca = 0.f;
    for (int k = t; k < n; k += 256) {
        int i = cand[2 * k], j = cand[2 * k + 1];
        if (pid[i] != pid[j]) {
            float d = sqrtf(fmaxf(edge_d2(emb, i, j), 0.f) + 1e-12f);
            if (d < 1.f) { float h = 1.f - d; ca += h * h; }
        }
    }
    float v = ca * (2.f / NPTS);
    if (t < 128) v += sigP[t] * (1.f / ESIG);
    if (t < 64)  v += rndP[t] * (1.f / ERND);
    block_reduce_store(v, out);
}

extern "C" void kernel_launch(void* const* d_in, const int* in_sizes, int n_in,
                              void* d_out, int out_size, void* d_ws, size_t ws_size,
                              hipStream_t stream) {
    const float* emb   = (const float*)d_in[0];
    const int*   sedge = (const int*)d_in[1];
    const int*   redge = (const int*)d_in[2];
    const int*   pid   = (const int*)d_in[3];
    float* out = (float*)d_out;

    float* sigP = (float*)d_ws;                       // 128
    float* rndP = sigP + 128;                         // 64
    int*   cnt  = (int*)(rndP + 64);                  // 4
    int*   cand = cnt + 4;                            // 2*CAP
    unsigned short* Ab = (unsigned short*)(cand + 2 * CAP);   // 16384*32
    unsigned short* Bb = Ab + (size_t)NPTS * KPAD;            // 16384*32

    fused_pre_kernel<<<256, 256, 0, stream>>>(emb, sedge, redge, pid, Ab, Bb, sigP, rndP, cnt);
    knn_mfma_kernel<<<NBLK, 512, 0, stream>>>(Ab, Bb, cnt, cand);
    finalize_kernel<<<1, 256, 0, stream>>>(emb, pid, cnt, cand, sigP, rndP, out);
}